// Round 17
// baseline (26.986 us; speedup 1.0000x reference)
//
#include <hip/hip_runtime.h>

// SigNet forward, closed-form depth-3 signature + Linear, CHANNEL-split 2x.
// B=256, L=256, CIN=8, C=9, SIG_CH=819, OUT=128.
//
// Per-l additive form (cross-term folded; validated R13-R16):
//   s2[i][j]    = sum_l w_i d_j
//   s3[i][j][k] = sum_l [ z_i d_j d_k + w_i d_j * M_l[k] ],  M = x_L - X
//   w = X - 0.5*D, z = 0.5*X - D/3
//
// Grid 512 = 2 blocks/batch, SPLIT BY CHANNEL i (block h=0: i 0..4;
// h=1: i 5..8 + s1). Each block does the FULL l-range -> no sig combine,
// and each block reads only ITS W rows -> no W duplication (R15's flaw).
// Partial y atomicAdd'ed into out (zeroed per call; 2 IEEE-commutative
// contributions -> deterministic). 512 threads -> VGPR 68, and the
// 36-acc (i, all-j, kt) body is R4-PROVEN no-spill at this shape:
// 17 LDS reads per q for 27 pairs (halves LDS-pipe pressure vs 12-acc).
// ~68 KB LDS -> 2 blocks/CU co-resident; desynced barriers overlap phases.

#define ROWF   260                    // table row stride (65 float4)
#define NR     32                     // l-ranges (2 float4-cols each)
#define AST    29                     // s3 dump stride (27 used)
#define DUMPF  (512 * AST)            // 14848 floats (covers 480 act threads)
#define S2CAP  (NR * 45)              // 1440 (block0's 45 s2 rows is the max)
#define U1SZ   (DUMPF + S2CAP)        // 16288 floats = 65.2 KB (tables alias)

__global__ __launch_bounds__(512) void signet_fwd(
    const float* __restrict__ inp,   // [256, 256, 8]
    const float* __restrict__ Wg,    // [819, 128]
    const float* __restrict__ bias,  // [128]
    float* __restrict__ out)         // [256, 128], pre-zeroed per call
{
    __shared__ float sig[820];
    __shared__ __align__(16) float u[U1SZ];

    float* Xt = u;                    // [9][260] (dead after main loop)
    float* Dt = u + 9 * ROWF;
    float* Mt = u + 18 * ROWF;        // x_L - X

    const int tid = threadIdx.x;
    const int b   = blockIdx.x >> 1;
    const int h   = blockIdx.x & 1;   // channel half: i in [IB, IB+NI)

    // ---- prep: full-L tables (column t = segment t+1, basepoint 0) ----
    {
        const int col = tid & 255;
        const float* rc = inp + (size_t)b * 2048 + (size_t)col * 8;
        const float* rl = inp + (size_t)b * 2048 + 255 * 8;
        if (tid < 256) {
            float4 c0 = *(const float4*)rc;
            float4 p0 = make_float4(0.f, 0.f, 0.f, 0.f);
            float  tp = 0.f;
            if (col > 0) { p0 = *(const float4*)(rc - 8); tp = (float)(col - 1) * (1.0f / 255.0f); }
            float4 xl0 = *(const float4*)rl;
            float cur[5] = { (float)col * (1.0f / 255.0f), c0.x, c0.y, c0.z, c0.w };
            float prv[5] = { tp, p0.x, p0.y, p0.z, p0.w };
            float xlv[5] = { 1.0f, xl0.x, xl0.y, xl0.z, xl0.w };
            #pragma unroll
            for (int c = 0; c < 5; ++c) {
                Xt[c * ROWF + col] = cur[c];
                Dt[c * ROWF + col] = cur[c] - prv[c];
                Mt[c * ROWF + col] = xlv[c] - cur[c];
            }
        } else {
            float4 c1 = *(const float4*)(rc + 4);
            float4 p1 = make_float4(0.f, 0.f, 0.f, 0.f);
            if (col > 0) p1 = *(const float4*)(rc - 4);
            float4 xl1 = *(const float4*)(rl + 4);
            float cur[4] = { c1.x, c1.y, c1.z, c1.w };
            float prv[4] = { p1.x, p1.y, p1.z, p1.w };
            float xlv[4] = { xl1.x, xl1.y, xl1.z, xl1.w };
            #pragma unroll
            for (int c = 0; c < 4; ++c) {
                Xt[(5 + c) * ROWF + col] = cur[c];
                Dt[(5 + c) * ROWF + col] = cur[c] - prv[c];
                Mt[(5 + c) * ROWF + col] = xlv[c] - cur[c];
            }
        }
    }
    __syncthreads();

    // ---- main: combos = (i_local, kt); NC = NI*3; range rr covers 2 f4-cols ----
    const int NI = h ? 4 : 5;
    const int IB = h ? 5 : 0;
    const int NC = NI * 3;               // 12 or 15
    int rr, lt;
    if (h) { rr = tid / 12; lt = tid - rr * 12; }
    else   { rr = tid / 15; lt = tid - rr * 15; }
    const int il = lt / 3;               // local i
    const int kt = lt - il * 3;          // k-triple
    const int ci = IB + il;
    const bool act = (rr < NR);          // 480 (h=0) or 384 (h=1) active

    float a[9][3];                       // [j][km]
    float s2a[9];
    #pragma unroll
    for (int j = 0; j < 9; ++j) { s2a[j] = 0.f; a[j][0] = 0.f; a[j][1] = 0.f; a[j][2] = 0.f; }

    if (act) {
        const float4* X4 = (const float4*)u;           // [9][65]
        const float4* D4 = X4 + 9 * 65;
        const float4* M4 = X4 + 18 * 65;
        const int k0 = 3 * kt;

        #pragma unroll
        for (int q = 0; q < 2; ++q) {
            const int idx = rr * 2 + q;
            const float4 Xi  = X4[ci * 65 + idx];
            const float4 Di  = D4[ci * 65 + idx];
            const float4 Mk0 = M4[(k0 + 0) * 65 + idx];
            const float4 Mk1 = M4[(k0 + 1) * 65 + idx];
            const float4 Mk2 = M4[(k0 + 2) * 65 + idx];
            const float4 Dk0 = D4[(k0 + 0) * 65 + idx];
            const float4 Dk1 = D4[(k0 + 1) * 65 + idx];
            const float4 Dk2 = D4[(k0 + 2) * 65 + idx];

            float4 w, z;
            w.x = fmaf(-0.5f, Di.x, Xi.x);
            w.y = fmaf(-0.5f, Di.y, Xi.y);
            w.z = fmaf(-0.5f, Di.z, Xi.z);
            w.w = fmaf(-0.5f, Di.w, Xi.w);
            z.x = fmaf(-(1.0f / 3.0f), Di.x, 0.5f * Xi.x);
            z.y = fmaf(-(1.0f / 3.0f), Di.y, 0.5f * Xi.y);
            z.z = fmaf(-(1.0f / 3.0f), Di.z, 0.5f * Xi.z);
            z.w = fmaf(-(1.0f / 3.0f), Di.w, 0.5f * Xi.w);

            #pragma unroll
            for (int j = 0; j < 9; ++j) {
                const float4 Dj = D4[j * 65 + idx];
                float4 uu, vv;
                uu.x = w.x * Dj.x;  uu.y = w.y * Dj.y;
                uu.z = w.z * Dj.z;  uu.w = w.w * Dj.w;
                vv.x = z.x * Dj.x;  vv.y = z.y * Dj.y;
                vv.z = z.z * Dj.z;  vv.w = z.w * Dj.w;
                s2a[j] += (uu.x + uu.y) + (uu.z + uu.w);

                a[j][0] = fmaf(vv.x, Dk0.x, fmaf(uu.x, Mk0.x, a[j][0]));
                a[j][0] = fmaf(vv.y, Dk0.y, fmaf(uu.y, Mk0.y, a[j][0]));
                a[j][0] = fmaf(vv.z, Dk0.z, fmaf(uu.z, Mk0.z, a[j][0]));
                a[j][0] = fmaf(vv.w, Dk0.w, fmaf(uu.w, Mk0.w, a[j][0]));

                a[j][1] = fmaf(vv.x, Dk1.x, fmaf(uu.x, Mk1.x, a[j][1]));
                a[j][1] = fmaf(vv.y, Dk1.y, fmaf(uu.y, Mk1.y, a[j][1]));
                a[j][1] = fmaf(vv.z, Dk1.z, fmaf(uu.z, Mk1.z, a[j][1]));
                a[j][1] = fmaf(vv.w, Dk1.w, fmaf(uu.w, Mk1.w, a[j][1]));

                a[j][2] = fmaf(vv.x, Dk2.x, fmaf(uu.x, Mk2.x, a[j][2]));
                a[j][2] = fmaf(vv.y, Dk2.y, fmaf(uu.y, Mk2.y, a[j][2]));
                a[j][2] = fmaf(vv.z, Dk2.z, fmaf(uu.z, Mk2.z, a[j][2]));
                a[j][2] = fmaf(vv.w, Dk2.w, fmaf(uu.w, Mk2.w, a[j][2]));
            }
        }
    }
    __syncthreads();   // tables dead; dump may alias

    // ---- dump: 27 floats/thread (stride 29) + s2a (kt==0 threads) ----
    if (act) {
        float* pa = u + tid * AST;
        #pragma unroll
        for (int j = 0; j < 9; ++j) {
            pa[j * 3 + 0] = a[j][0];
            pa[j * 3 + 1] = a[j][1];
            pa[j * 3 + 2] = a[j][2];
        }
        if (kt == 0) {
            float* ps = u + DUMPF + (rr * NI + il) * 9;
            #pragma unroll
            for (int j = 0; j < 9; ++j) ps[j] = s2a[j];
        }
    }
    if (h && tid < 9) {
        sig[tid] = (tid == 0) ? 1.0f
                              : inp[(size_t)b * 2048 + 255 * 8 + (tid - 1)];
    }
    __syncthreads();

    // ---- combine s2 -> sig[9 + i*9 + j] (this block's i only) ----
    if (tid < NI * 9) {
        const int i2 = tid / 9;
        const int j2 = tid - i2 * 9;
        float s = 0.f;
        #pragma unroll
        for (int r = 0; r < NR; ++r) s += u[DUMPF + (r * NI + i2) * 9 + j2];
        sig[9 + (IB + i2) * 9 + j2] = s;
    }
    // ---- combine s3 -> sig[90 + i*81 + rem] (this block's i only) ----
    if (tid < NI * 81) {
        const int i3  = tid / 81;
        const int rem = tid - i3 * 81;
        const int j3  = rem / 9;
        const int k3  = rem - j3 * 9;
        const int kt3 = k3 / 3, km3 = k3 - kt3 * 3;
        const int toff = (i3 * 3 + kt3) * AST + j3 * 3 + km3;
        float s = 0.f;
        #pragma unroll
        for (int r = 0; r < NR; ++r) s += u[(r * NC) * AST + toff];
        sig[90 + (IB + i3) * 81 + rem] = s;
    }
    __syncthreads();

    // ---- partial linear over this block's channel ranges ----
    {
        const int oq = tid & 31;     // outputs 4*oq..4*oq+3
        const int sl = tid >> 5;     // channel slice 0..15
        float4 acc = make_float4(0.f, 0.f, 0.f, 0.f);
        const float4* Wq = (const float4*)Wg;
        if (h == 0) {
            // s2 rows [9,54), s3 rows [90,495)
            for (int ch = 9 + sl; ch < 54; ch += 16) {
                const float s = sig[ch];
                const float4 wv = Wq[(size_t)ch * 32 + oq];
                acc.x = fmaf(s, wv.x, acc.x); acc.y = fmaf(s, wv.y, acc.y);
                acc.z = fmaf(s, wv.z, acc.z); acc.w = fmaf(s, wv.w, acc.w);
            }
            for (int ch = 90 + sl; ch < 495; ch += 16) {
                const float s = sig[ch];
                const float4 wv = Wq[(size_t)ch * 32 + oq];
                acc.x = fmaf(s, wv.x, acc.x); acc.y = fmaf(s, wv.y, acc.y);
                acc.z = fmaf(s, wv.z, acc.z); acc.w = fmaf(s, wv.w, acc.w);
            }
        } else {
            // s1 rows [0,9), s2 rows [54,90), s3 rows [495,819)
            for (int ch = sl; ch < 9; ch += 16) {
                const float s = sig[ch];
                const float4 wv = Wq[(size_t)ch * 32 + oq];
                acc.x = fmaf(s, wv.x, acc.x); acc.y = fmaf(s, wv.y, acc.y);
                acc.z = fmaf(s, wv.z, acc.z); acc.w = fmaf(s, wv.w, acc.w);
            }
            for (int ch = 54 + sl; ch < 90; ch += 16) {
                const float s = sig[ch];
                const float4 wv = Wq[(size_t)ch * 32 + oq];
                acc.x = fmaf(s, wv.x, acc.x); acc.y = fmaf(s, wv.y, acc.y);
                acc.z = fmaf(s, wv.z, acc.z); acc.w = fmaf(s, wv.w, acc.w);
            }
            for (int ch = 495 + sl; ch < 819; ch += 16) {
                const float s = sig[ch];
                const float4 wv = Wq[(size_t)ch * 32 + oq];
                acc.x = fmaf(s, wv.x, acc.x); acc.y = fmaf(s, wv.y, acc.y);
                acc.z = fmaf(s, wv.z, acc.z); acc.w = fmaf(s, wv.w, acc.w);
            }
        }
        float4* pbuf = (float4*)u;               // aliases dead dump region
        pbuf[sl * 32 + oq] = acc;
    }
    __syncthreads();
    if (tid < 32) {
        const float4* pbuf = (const float4*)u;
        float4 r = pbuf[tid];
        #pragma unroll
        for (int s = 1; s < 16; ++s) {
            const float4 p = pbuf[s * 32 + tid];
            r.x += p.x; r.y += p.y; r.z += p.z; r.w += p.w;
        }
        if (h) {
            const float4 bv = ((const float4*)bias)[tid];
            r.x += bv.x; r.y += bv.y; r.z += bv.z; r.w += bv.w;
        }
        float* dst = out + (size_t)b * 128 + tid * 4;
        atomicAdd(dst + 0, r.x);
        atomicAdd(dst + 1, r.y);
        atomicAdd(dst + 2, r.z);
        atomicAdd(dst + 3, r.w);
    }
}

extern "C" void kernel_launch(void* const* d_in, const int* in_sizes, int n_in,
                              void* d_out, int out_size, void* d_ws, size_t ws_size,
                              hipStream_t stream) {
    const float* inp  = (const float*)d_in[0];
    const float* Wp   = (const float*)d_in[1];
    const float* bias = (const float*)d_in[2];
    float* outp = (float*)d_out;
    (void)in_sizes; (void)n_in; (void)d_ws; (void)ws_size;

    hipMemsetAsync(outp, 0, (size_t)out_size * sizeof(float), stream);
    hipLaunchKernelGGL(signet_fwd, dim3(512), dim3(512), 0, stream,
                       inp, Wp, bias, outp);
}

// Round 18
// 17.689 us; speedup vs baseline: 1.5255x; 1.5255x over previous
//
#include <hip/hip_runtime.h>

// SigNet forward, closed-form (scan-free) depth-3 signature + Linear.
// B=256, L=256, CIN=8, C=9, SIG_CH=819, OUT=128.
//
// Fully-folded per-l additive form (cross-term inside the sum; validated
// R13/R14 at this exact thread shape):
//   s1[i]       = x_L[i]
//   s2[i][j]    = sum_l w_i d_j
//   s3[i][j][k] = sum_l [ z_i d_j d_k + w_i d_j * M_l[k] ],  M = x_L - X
//   w = X - 0.5*D, z = 0.5*X - D/3
//
// One block per batch, 1024 threads (16 waves/CU), single dispatch.
// 8 l-ranges x 81 (i, j-triple, k-triple) owners = 648 active threads,
// 12 accumulators/thread (VGPR 64, no spill - R10/R14 proven). M-fold
// makes the s2 and s3 combines independent -> merged into ONE phase
// (5 barriers instead of R10's 6, no 729-fma dependent chain).

#define RANGES  8
#define TPR     81
#define NACT    (RANGES * TPR)        // 648
#define PSTR    13                    // dump stride (12 used, odd)
#define U1SZ    (NACT * PSTR)         // 8424 floats; tables (7020) alias front

__global__ __launch_bounds__(1024) void signet_fwd(
    const float* __restrict__ inp,   // [256, 256, 8]
    const float* __restrict__ Wg,    // [819, 128]
    const float* __restrict__ bias,  // [128]
    float* __restrict__ out)         // [256, 128]
{
    __shared__ float sig[820];
    __shared__ __align__(16) float u[U1SZ];

    float* Xt = u;                    // [9][260] (dead after main loop)
    float* Dt = u + 9 * 260;
    float* Mt = u + 18 * 260;         // x_L - X

    const int tid = threadIdx.x;
    const int b   = blockIdx.x;

    // ---- prep: X/D/M tables (column t = segment t+1, basepoint 0) + s1 ----
    if (tid < 512) {
        const int t = tid & 255;
        const float* rc = inp + (size_t)b * 2048 + (size_t)t * 8;
        const float* rl = inp + (size_t)b * 2048 + 255 * 8;
        if (tid < 256) {
            float4 c0 = *(const float4*)rc;
            float4 p0 = make_float4(0.f, 0.f, 0.f, 0.f);
            float  tp = 0.f;
            if (t > 0) { p0 = *(const float4*)(rc - 8); tp = (float)(t - 1) * (1.0f / 255.0f); }
            float4 xl0 = *(const float4*)rl;
            float cur[5] = { (float)t * (1.0f / 255.0f), c0.x, c0.y, c0.z, c0.w };
            float prv[5] = { tp, p0.x, p0.y, p0.z, p0.w };
            float xlv[5] = { 1.0f, xl0.x, xl0.y, xl0.z, xl0.w };
            #pragma unroll
            for (int c = 0; c < 5; ++c) {
                Xt[c * 260 + t] = cur[c];
                Dt[c * 260 + t] = cur[c] - prv[c];
                Mt[c * 260 + t] = xlv[c] - cur[c];
            }
        } else {
            float4 c1 = *(const float4*)(rc + 4);
            float4 p1 = make_float4(0.f, 0.f, 0.f, 0.f);
            if (t > 0) p1 = *(const float4*)(rc - 4);
            float4 xl1 = *(const float4*)(rl + 4);
            float cur[4] = { c1.x, c1.y, c1.z, c1.w };
            float prv[4] = { p1.x, p1.y, p1.z, p1.w };
            float xlv[4] = { xl1.x, xl1.y, xl1.z, xl1.w };
            #pragma unroll
            for (int c = 0; c < 4; ++c) {
                Xt[(5 + c) * 260 + t] = cur[c];
                Dt[(5 + c) * 260 + t] = cur[c] - prv[c];
                Mt[(5 + c) * 260 + t] = xlv[c] - cur[c];
            }
        }
    }
    if (tid < 9) {
        sig[tid] = (tid == 0) ? 1.0f
                              : inp[(size_t)b * 2048 + 255 * 8 + (tid - 1)];
    }
    __syncthreads();

    // ---- main: range rr = tid/81 handles float4 cols [rr*8, rr*8+8) ----
    const bool act = (tid < NACT);
    const int  rr  = tid / TPR;
    const int  lt  = tid - rr * TPR;     // 0..80
    const int  ii  = lt / 9;             // channel i
    const int  jk  = lt - ii * 9;
    const int  jt  = jk / 3;             // j-triple: j = 3*jt+jm
    const int  kt  = jk - jt * 3;        // k-triple: k = 3*kt+km

    float a[3][3];                       // [jm][km]
    float s2a[3];
    #pragma unroll
    for (int jm = 0; jm < 3; ++jm) {
        s2a[jm] = 0.f;
        a[jm][0] = 0.f; a[jm][1] = 0.f; a[jm][2] = 0.f;
    }

    if (act) {
        const float4* X4 = (const float4*)u;             // [9][65]
        const float4* D4 = X4 + 9 * 65;
        const float4* M4 = X4 + 18 * 65;

        #pragma unroll
        for (int q = 0; q < 8; ++q) {
            const int idx = rr * 8 + q;
            const float4 Xi = X4[ii * 65 + idx];
            const float4 Di = D4[ii * 65 + idx];
            float4 w, z;
            w.x = fmaf(-0.5f, Di.x, Xi.x);
            w.y = fmaf(-0.5f, Di.y, Xi.y);
            w.z = fmaf(-0.5f, Di.z, Xi.z);
            w.w = fmaf(-0.5f, Di.w, Xi.w);
            z.x = fmaf(-(1.0f / 3.0f), Di.x, 0.5f * Xi.x);
            z.y = fmaf(-(1.0f / 3.0f), Di.y, 0.5f * Xi.y);
            z.z = fmaf(-(1.0f / 3.0f), Di.z, 0.5f * Xi.z);
            z.w = fmaf(-(1.0f / 3.0f), Di.w, 0.5f * Xi.w);

            float4 uu[3], vv[3];
            #pragma unroll
            for (int jm = 0; jm < 3; ++jm) {
                const float4 Dj = D4[(3 * jt + jm) * 65 + idx];
                uu[jm].x = w.x * Dj.x;  uu[jm].y = w.y * Dj.y;
                uu[jm].z = w.z * Dj.z;  uu[jm].w = w.w * Dj.w;
                vv[jm].x = z.x * Dj.x;  vv[jm].y = z.y * Dj.y;
                vv[jm].z = z.z * Dj.z;  vv[jm].w = z.w * Dj.w;
                s2a[jm] += (uu[jm].x + uu[jm].y) + (uu[jm].z + uu[jm].w);
            }
            #pragma unroll
            for (int km = 0; km < 3; ++km) {
                const float4 Dk = D4[(3 * kt + km) * 65 + idx];
                const float4 Mk = M4[(3 * kt + km) * 65 + idx];
                #pragma unroll
                for (int jm = 0; jm < 3; ++jm) {
                    a[jm][km] = fmaf(vv[jm].x, Dk.x, fmaf(uu[jm].x, Mk.x, a[jm][km]));
                    a[jm][km] = fmaf(vv[jm].y, Dk.y, fmaf(uu[jm].y, Mk.y, a[jm][km]));
                    a[jm][km] = fmaf(vv[jm].z, Dk.z, fmaf(uu[jm].z, Mk.z, a[jm][km]));
                    a[jm][km] = fmaf(vv[jm].w, Dk.w, fmaf(uu[jm].w, Mk.w, a[jm][km]));
                }
            }
        }
    }
    __syncthreads();   // last table read above; dump may now alias tables

    // ---- dump partials (12 floats/thread, stride 13) ----
    if (act) {
        float* pa = u + tid * PSTR;
        #pragma unroll
        for (int jm = 0; jm < 3; ++jm) {
            pa[jm * 3 + 0] = a[jm][0];
            pa[jm * 3 + 1] = a[jm][1];
            pa[jm * 3 + 2] = a[jm][2];
        }
        pa[9]  = s2a[0];
        pa[10] = s2a[1];
        pa[11] = s2a[2];
    }
    __syncthreads();

    // ---- merged combine: s2 and s3 are independent (cross-term folded) ----
    if (tid < 81) {
        const int i2  = tid / 9;
        const int j2  = tid - i2 * 9;
        const int jt2 = j2 / 3;
        const int jm2 = j2 - jt2 * 3;
        const int base = (i2 * 9 + jt2 * 3) * PSTR + 9 + jm2;   // kt == 0 slot
        float s = 0.f;
        #pragma unroll
        for (int c = 0; c < RANGES; ++c) s += u[c * TPR * PSTR + base];
        sig[9 + tid] = s;
    }
    if (tid < 729) {
        const int e   = tid;
        const int i3  = e / 81;
        const int rem = e - i3 * 81;
        const int j3  = rem / 9;
        const int k3  = rem - j3 * 9;
        const int jt3 = j3 / 3, jm3 = j3 - jt3 * 3;
        const int kt3 = k3 / 3, km3 = k3 - kt3 * 3;
        const int base = (i3 * 9 + jt3 * 3 + kt3) * PSTR + jm3 * 3 + km3;
        float s = 0.f;
        #pragma unroll
        for (int c = 0; c < RANGES; ++c) s += u[c * TPR * PSTR + base];
        sig[90 + e] = s;                 // no cross-term fma needed
    }
    __syncthreads();

    // ---- linear: out[b][o] = bias[o] + sum_ch sig[ch]*Wg[ch][o] ----
    {
        const int oq = tid & 31;     // outputs 4*oq..4*oq+3
        const int sl = tid >> 5;     // channel slice 0..31
        float4 acc = make_float4(0.f, 0.f, 0.f, 0.f);
        const float4* Wq = (const float4*)Wg;
        #pragma unroll 4
        for (int ch = sl; ch < 819; ch += 32) {
            const float s = sig[ch];
            const float4 wv = Wq[(size_t)ch * 32 + oq];
            acc.x = fmaf(s, wv.x, acc.x);
            acc.y = fmaf(s, wv.y, acc.y);
            acc.z = fmaf(s, wv.z, acc.z);
            acc.w = fmaf(s, wv.w, acc.w);
        }
        float4* pbuf = (float4*)u;               // aliases dead dump region
        pbuf[sl * 32 + oq] = acc;
    }
    __syncthreads();
    if (tid < 32) {
        const float4* pbuf = (const float4*)u;
        float4 r = pbuf[tid];
        #pragma unroll
        for (int s = 1; s < 32; ++s) {
            const float4 p = pbuf[s * 32 + tid];
            r.x += p.x; r.y += p.y; r.z += p.z; r.w += p.w;
        }
        const float4 bv = ((const float4*)bias)[tid];
        r.x += bv.x; r.y += bv.y; r.z += bv.z; r.w += bv.w;
        ((float4*)(out + (size_t)b * 128))[tid] = r;
    }
}

extern "C" void kernel_launch(void* const* d_in, const int* in_sizes, int n_in,
                              void* d_out, int out_size, void* d_ws, size_t ws_size,
                              hipStream_t stream) {
    const float* inp  = (const float*)d_in[0];
    const float* Wp   = (const float*)d_in[1];
    const float* bias = (const float*)d_in[2];
    float* outp = (float*)d_out;
    (void)in_sizes; (void)n_in; (void)out_size; (void)d_ws; (void)ws_size;

    hipLaunchKernelGGL(signet_fwd, dim3(256), dim3(1024), 0, stream,
                       inp, Wp, bias, outp);
}